// Round 7
// baseline (1003.243 us; speedup 1.0000x reference)
//
#include <hip/hip_runtime.h>

// Problem constants (fixed by the reference): T=512, B=64, I=256, H=512.
#define T_DIM 512
#define B_DIM 64
#define I_DIM 256
#define H_DIM 512
#define BH_DIM (B_DIM * H_DIM)   // 32768

// ---------------------------------------------------------------------------
// Round-13: xw_gemm (unchanged) + single-stream scan with P-shaves.
//
// R12 lesson: total = T x P (P = block iteration period); extra streams only
// grow P. P's terms are detect latency + barrier drain + fma. Shaves vs R11:
//  1. Speculative poll loads issued at loop BOTTOM right after publish
//     (R12-proven pattern): first sample lands ~RT after partners' pubs ->
//     detect ~1 RT instead of ~2 serial RTs from a loop-top cold start.
//  2. xw prefetch issued AFTER the barrier (R11 had it before: the
//     compiler's vmcnt(0)-before-s_barrier made every barrier eat a ~600cy
//     MALL load). Now it drains at the NEXT barrier, ~P later, retired.
//  3. Pair-polls: 192 pollers x 16B (two tagged words), R7-proven mapping.
// Everything else identical to R11 (740us scan): 256 blocks = 4 row-chunks
// x 64 batches, 512 thr, W_hh chunk in regs (w[4][8]), DPP 16-lane reduce,
// agent-scope tagged words (tag = t+1), parity double-buffer, one barrier
// per step.
// ---------------------------------------------------------------------------

// ---------------- Kernel 1: xw pre-pass GEMM (unchanged, R11) ----------------
__global__ __launch_bounds__(256) void xw_gemm(
    const float* __restrict__ x, const float* __restrict__ wih,
    const float* __restrict__ bih, const float* __restrict__ bhh,
    float* __restrict__ out) {
  __shared__ __align__(16) float As[32][128];  // [k][m]
  __shared__ __align__(16) float Bs[32][128];  // [k][n]

  const int bm = blockIdx.x >> 2;   // 0..255 (m-tile)
  const int bn = blockIdx.x & 3;    // 0..3   (n-tile)
  const int m0 = bm * 128, n0 = bn * 128;
  const int tid = threadIdx.x;      // 0..255
  const int tx = tid & 15, ty = tid >> 4;
  const int ml = tid & 127, kq = tid >> 7;  // staging map

  float acc[8][8];
#pragma unroll
  for (int r = 0; r < 8; r++)
#pragma unroll
    for (int c = 0; c < 8; c++) acc[r][c] = 0.f;

  for (int kc = 0; kc < I_DIM; kc += 32) {
    const float4* xr = (const float4*)(x + (size_t)(m0 + ml) * I_DIM + kc + kq * 16);
    const float4* br = (const float4*)(wih + (size_t)(n0 + ml) * I_DIM + kc + kq * 16);
    float4 av[4], bv[4];
#pragma unroll
    for (int j = 0; j < 4; j++) { av[j] = xr[j]; bv[j] = br[j]; }

    __syncthreads();
#pragma unroll
    for (int j = 0; j < 4; j++) {
      const int k = kq * 16 + j * 4;
      As[k + 0][ml] = av[j].x; As[k + 1][ml] = av[j].y;
      As[k + 2][ml] = av[j].z; As[k + 3][ml] = av[j].w;
      Bs[k + 0][ml] = bv[j].x; Bs[k + 1][ml] = bv[j].y;
      Bs[k + 2][ml] = bv[j].z; Bs[k + 3][ml] = bv[j].w;
    }
    __syncthreads();

#pragma unroll 4
    for (int kk = 0; kk < 32; kk++) {
      const float4 a0 = *(const float4*)&As[kk][ty * 4];
      const float4 a1 = *(const float4*)&As[kk][64 + ty * 4];
      const float4 b0 = *(const float4*)&Bs[kk][tx * 4];
      const float4 b1 = *(const float4*)&Bs[kk][64 + tx * 4];
      const float ar[8] = {a0.x, a0.y, a0.z, a0.w, a1.x, a1.y, a1.z, a1.w};
      const float br_[8] = {b0.x, b0.y, b0.z, b0.w, b1.x, b1.y, b1.z, b1.w};
#pragma unroll
      for (int r = 0; r < 8; r++)
#pragma unroll
        for (int c = 0; c < 8; c++) acc[r][c] = fmaf(ar[r], br_[c], acc[r][c]);
    }
  }

  const float4 bi0 = *(const float4*)(bih + n0 + tx * 4);
  const float4 bh0 = *(const float4*)(bhh + n0 + tx * 4);
  const float4 bi1 = *(const float4*)(bih + n0 + 64 + tx * 4);
  const float4 bh1 = *(const float4*)(bhh + n0 + 64 + tx * 4);
  const float4 bb0 = make_float4(bi0.x + bh0.x, bi0.y + bh0.y, bi0.z + bh0.z, bi0.w + bh0.w);
  const float4 bb1 = make_float4(bi1.x + bh1.x, bi1.y + bh1.y, bi1.z + bh1.z, bi1.w + bh1.w);

#pragma unroll
  for (int r = 0; r < 8; r++) {
    const int m = m0 + ((r < 4) ? (ty * 4 + r) : (64 + ty * 4 + (r - 4)));
    float4* orow = (float4*)(out + (size_t)m * H_DIM + n0);
    orow[tx] = make_float4(acc[r][0] + bb0.x, acc[r][1] + bb0.y,
                           acc[r][2] + bb0.z, acc[r][3] + bb0.w);
    orow[16 + tx] = make_float4(acc[r][4] + bb1.x, acc[r][5] + bb1.y,
                                acc[r][6] + bb1.z, acc[r][7] + bb1.w);
  }
}

// ---------------- Kernel 2: recurrent scan ----------------

// 16-lane sum on the VALU pipe (DPP): quad_perm 0xB1, 0x4E, row_ror:4, :8.
__device__ __forceinline__ float row16_sum(float v) {
  int m;
  m = __builtin_amdgcn_update_dpp(0, __float_as_int(v), 0xB1, 0xF, 0xF, true);
  v += __int_as_float(m);
  m = __builtin_amdgcn_update_dpp(0, __float_as_int(v), 0x4E, 0xF, 0xF, true);
  v += __int_as_float(m);
  m = __builtin_amdgcn_update_dpp(0, __float_as_int(v), 0x124, 0xF, 0xF, true);
  v += __int_as_float(m);
  m = __builtin_amdgcn_update_dpp(0, __float_as_int(v), 0x128, 0xF, 0xF, true);
  v += __int_as_float(m);
  return v;
}

// hh accumulation: 4 rows x 8 float4 + 16-lane reduce; result valid cg<4.
__device__ __forceinline__ float hh_acc(const float* hb,
                                        const float4 (&w)[4][8], int cg) {
  float a0 = 0.f, a1 = 0.f, a2 = 0.f, a3 = 0.f;
#pragma unroll
  for (int i = 0; i < 8; i++) {
    const float4 hv = ((const float4*)hb)[i * 16 + cg];
    a0 = fmaf(w[0][i].x, hv.x, a0); a0 = fmaf(w[0][i].y, hv.y, a0);
    a0 = fmaf(w[0][i].z, hv.z, a0); a0 = fmaf(w[0][i].w, hv.w, a0);
    a1 = fmaf(w[1][i].x, hv.x, a1); a1 = fmaf(w[1][i].y, hv.y, a1);
    a1 = fmaf(w[1][i].z, hv.z, a1); a1 = fmaf(w[1][i].w, hv.w, a1);
    a2 = fmaf(w[2][i].x, hv.x, a2); a2 = fmaf(w[2][i].y, hv.y, a2);
    a2 = fmaf(w[2][i].z, hv.z, a2); a2 = fmaf(w[2][i].w, hv.w, a2);
    a3 = fmaf(w[3][i].x, hv.x, a3); a3 = fmaf(w[3][i].y, hv.y, a3);
    a3 = fmaf(w[3][i].z, hv.z, a3); a3 = fmaf(w[3][i].w, hv.w, a3);
  }
  a0 = row16_sum(a0);
  a1 = row16_sum(a1);
  a2 = row16_sum(a2);
  a3 = row16_sum(a3);
  return (cg == 0) ? a0 : (cg == 1) ? a1 : (cg == 2) ? a2 : a3;
}

__global__ __launch_bounds__(512, 2) void rnn_scan3(
    const float* __restrict__ whh, float* __restrict__ out,
    unsigned long long* __restrict__ stage) {
  __shared__ __align__(16) float hbuf[2][H_DIM];  // 4 KB h double buffer

  const int b   = blockIdx.x & 63;
  const int rb  = blockIdx.x >> 6;       // row-chunk 0..3
  const int tid = threadIdx.x;           // 0..511
  const int rg  = tid >> 4;              // 0..31
  const int cg  = tid & 15;              // 0..15
  const int j0  = rb * 128 + rg * 4;     // first of my 4 rows
  const int jj  = j0 + cg;               // publish index (cg<4 lanes)

  // pair-poll: 192 pollers, one pair of adjacent 8B words each (384 words =
  // partner elements; own pairs [rb*64, rb*64+64) of 256 skipped)
  const int pjp = (tid < rb * 64) ? tid : tid + 64;  // valid for tid<192
  const bool poller = (tid < 192);

  // ---- W_hh chunk -> registers (once) ----
  float4 w[4][8];
#pragma unroll
  for (int r = 0; r < 4; r++) {
    const float4* wr = (const float4*)(whh + (size_t)(j0 + r) * H_DIM);
#pragma unroll
    for (int i = 0; i < 8; i++) w[r][i] = wr[i * 16 + cg];
  }

  float* __restrict__ outb = out + (size_t)b * H_DIM;  // t-stride = BH_DIM
  unsigned long long* __restrict__ stg0 = stage + (size_t)b * H_DIM;
  unsigned long long* __restrict__ stg1 = stage + (size_t)(64 + b) * H_DIM;

  float hlast = 0.f;

  // ---- t = 0: h_0 = relu(xw_0); publish (tag 1, parity 0) ----
  if (cg < 4) {
    const float h = fmaxf(outb[jj], 0.f);
    union { float f; unsigned int u; } cv; cv.f = h;
    __hip_atomic_store(&stg0[jj], (1ULL << 32) | (unsigned long long)cv.u,
                       __ATOMIC_RELAXED, __HIP_MEMORY_SCOPE_AGENT);
    __builtin_nontemporal_store(h, &outb[jj]);
    hbuf[0][jj] = h;
    hlast = h;
  }

  // prologue: speculative poll loads for t=1 (parity 0) + xw for t=1
  unsigned long long* slot = stg0 + 2 * pjp;
  unsigned long long v0 = 0, v1 = 0;
  if (poller) {
    v0 = __hip_atomic_load(slot, __ATOMIC_RELAXED, __HIP_MEMORY_SCOPE_AGENT);
    v1 = __hip_atomic_load(slot + 1, __ATOMIC_RELAXED,
                           __HIP_MEMORY_SCOPE_AGENT);
  }
  float xwv = 0.f;
  if (cg < 4)
    xwv = __builtin_nontemporal_load(&outb[(size_t)BH_DIM + jj]);

  // ---- main scan ----
  for (int t = 1; t < T_DIM; t++) {
    const int p = (t - 1) & 1;  // parity of h_{t-1}
    const unsigned int want = (unsigned int)t;  // tag carried by h_{t-1}
    float* o_t = outb + (size_t)t * BH_DIM;

    // A. finish the poll (spec loads from loop bottom usually hit)
    if (poller) {
      while ((unsigned int)(v0 >> 32) != want ||
             (unsigned int)(v1 >> 32) != want) {
        v0 = __hip_atomic_load(slot, __ATOMIC_RELAXED,
                               __HIP_MEMORY_SCOPE_AGENT);
        v1 = __hip_atomic_load(slot + 1, __ATOMIC_RELAXED,
                               __HIP_MEMORY_SCOPE_AGENT);
      }
      union { unsigned int u; float f; } c0, c1;
      c0.u = (unsigned int)v0; c1.u = (unsigned int)v1;
      hbuf[p][2 * pjp] = c0.f;
      hbuf[p][2 * pjp + 1] = c1.f;
    }

    __syncthreads();  // h_{t-1} complete in LDS; NO global load pending here

    // B. xw prefetch for t+1 (post-barrier: drains only at the NEXT
    //    barrier, ~P cycles later, long retired; consumed at next pub)
    float xw_n = 0.f;
    if (cg < 4 && t + 1 < T_DIM)
      xw_n = __builtin_nontemporal_load(&outb[(size_t)(t + 1) * BH_DIM + jj]);

    // C. hh-fma + DPP reduce
    const float acc = hh_acc(hbuf[p], w, cg);

    // D. publish h_t (tag t+1; 16 contiguous tagged words per wave)
    if (cg < 4) {
      const float h = fmaxf(acc + xwv, 0.f);
      union { float f; unsigned int u; } cv; cv.f = h;
      unsigned long long* sb = (t & 1) ? stg1 : stg0;
      __hip_atomic_store(&sb[jj],
                         ((unsigned long long)(unsigned int)(t + 1) << 32) |
                             (unsigned long long)cv.u,
                         __ATOMIC_RELAXED, __HIP_MEMORY_SCOPE_AGENT);
      __builtin_nontemporal_store(h, &o_t[jj]);  // output[t,b,j]
      hbuf[t & 1][jj] = h;    // own rows for next step
      hlast = h;
    }

    // E. speculative poll loads for t+1 (issued right after publish; the
    //    partners' pubs happen ~now, so these sample ~RT later -> likely
    //    hit. Consumed at next loop top BEFORE the barrier -> no drain.)
    if (poller) {
      slot = ((t & 1) ? stg1 : stg0) + 2 * pjp;
      v0 = __hip_atomic_load(slot, __ATOMIC_RELAXED,
                             __HIP_MEMORY_SCOPE_AGENT);
      v1 = __hip_atomic_load(slot + 1, __ATOMIC_RELAXED,
                             __HIP_MEMORY_SCOPE_AGENT);
    }

    xwv = xw_n;
  }

  // h_final = h_{T-1}
  if (cg < 4) {
    __builtin_nontemporal_store(
        hlast, &out[(size_t)T_DIM * BH_DIM + (size_t)b * H_DIM + jj]);
  }
}

extern "C" void kernel_launch(void* const* d_in, const int* in_sizes, int n_in,
                              void* d_out, int out_size, void* d_ws, size_t ws_size,
                              hipStream_t stream) {
  const float* x   = (const float*)d_in[0];  // [T,B,I]
  const float* wih = (const float*)d_in[1];  // [H,I]
  const float* whh = (const float*)d_in[2];  // [H,H]
  const float* bih = (const float*)d_in[3];  // [H]
  const float* bhh = (const float*)d_in[4];  // [H]
  float* out = (float*)d_out;                // [T,B,H] output ++ [B,H] h_final
  // staging: 2 parities x 64 batches x 512 tagged 8B words = 512 KB
  unsigned long long* stage = (unsigned long long*)d_ws;

  // Pass 1: xw = x @ wih^T + bih + bhh  -> written into out[0 .. T*B*H)
  xw_gemm<<<1024, 256, 0, stream>>>(x, wih, bih, bhh, out);
  // Pass 2: single-stream scan with spec-poll + post-barrier xw prefetch
  rnn_scan3<<<256, 512, 0, stream>>>(whh, out, stage);
}

// Round 8
// 885.386 us; speedup vs baseline: 1.1331x; 1.1331x over previous
//
#include <hip/hip_runtime.h>

// Problem constants (fixed by the reference): T=512, B=64, I=256, H=512.
#define T_DIM 512
#define B_DIM 64
#define I_DIM 256
#define H_DIM 512
#define BH_DIM (B_DIM * H_DIM)   // 32768

// ---------------------------------------------------------------------------
// Round-14: xw_gemm (unchanged) + R11 scan with vmcnt-decoupling reorders.
//
// Key realization: vmcnt is a single in-order counter. A poll load issued
// AFTER the publish/out stores can only be consumed via s_waitcnt vmcnt(0),
// which also waits for those stores' completion acks from MALL (~600-1000
// cy). R11 paid that EVERY step at the poll; it also paid a fresh ~600cy
// load RT at the barrier (xw load issued between poll and barrier; the
// barrier's vmcnt(0) drains it). Fixes vs R11 (ONLY these two):
//  1. Speculative poll load for step t+1 issued at loop bottom BEFORE the
//     publish/out stores (poll of partners' slots is independent of my own
//     publish). Loop-top check then needs only vmcnt(2) -- newer stores
//     stay outstanding. sched_barrier(0) pins the issue order.
//  2. xw prefetch issued AFTER the barrier (drains at the NEXT barrier,
//     ~P cycles later, long retired).
// Pollers: R11's proven 384 x single-word mapping. Everything else is
// byte-identical to R11's rnn_scan (740us): 256 blocks = 4 row-chunks x 64
// batches, 512 thr, W_hh chunk in regs (w[4][8]), DPP 16-lane reduce,
// agent-scope tagged words (tag = t+1), parity double-buffer, one barrier
// per step.
// ---------------------------------------------------------------------------

// ---------------- Kernel 1: xw pre-pass GEMM (unchanged, R11) ----------------
__global__ __launch_bounds__(256) void xw_gemm(
    const float* __restrict__ x, const float* __restrict__ wih,
    const float* __restrict__ bih, const float* __restrict__ bhh,
    float* __restrict__ out) {
  __shared__ __align__(16) float As[32][128];  // [k][m]
  __shared__ __align__(16) float Bs[32][128];  // [k][n]

  const int bm = blockIdx.x >> 2;   // 0..255 (m-tile)
  const int bn = blockIdx.x & 3;    // 0..3   (n-tile)
  const int m0 = bm * 128, n0 = bn * 128;
  const int tid = threadIdx.x;      // 0..255
  const int tx = tid & 15, ty = tid >> 4;
  const int ml = tid & 127, kq = tid >> 7;  // staging map

  float acc[8][8];
#pragma unroll
  for (int r = 0; r < 8; r++)
#pragma unroll
    for (int c = 0; c < 8; c++) acc[r][c] = 0.f;

  for (int kc = 0; kc < I_DIM; kc += 32) {
    const float4* xr = (const float4*)(x + (size_t)(m0 + ml) * I_DIM + kc + kq * 16);
    const float4* br = (const float4*)(wih + (size_t)(n0 + ml) * I_DIM + kc + kq * 16);
    float4 av[4], bv[4];
#pragma unroll
    for (int j = 0; j < 4; j++) { av[j] = xr[j]; bv[j] = br[j]; }

    __syncthreads();
#pragma unroll
    for (int j = 0; j < 4; j++) {
      const int k = kq * 16 + j * 4;
      As[k + 0][ml] = av[j].x; As[k + 1][ml] = av[j].y;
      As[k + 2][ml] = av[j].z; As[k + 3][ml] = av[j].w;
      Bs[k + 0][ml] = bv[j].x; Bs[k + 1][ml] = bv[j].y;
      Bs[k + 2][ml] = bv[j].z; Bs[k + 3][ml] = bv[j].w;
    }
    __syncthreads();

#pragma unroll 4
    for (int kk = 0; kk < 32; kk++) {
      const float4 a0 = *(const float4*)&As[kk][ty * 4];
      const float4 a1 = *(const float4*)&As[kk][64 + ty * 4];
      const float4 b0 = *(const float4*)&Bs[kk][tx * 4];
      const float4 b1 = *(const float4*)&Bs[kk][64 + tx * 4];
      const float ar[8] = {a0.x, a0.y, a0.z, a0.w, a1.x, a1.y, a1.z, a1.w};
      const float br_[8] = {b0.x, b0.y, b0.z, b0.w, b1.x, b1.y, b1.z, b1.w};
#pragma unroll
      for (int r = 0; r < 8; r++)
#pragma unroll
        for (int c = 0; c < 8; c++) acc[r][c] = fmaf(ar[r], br_[c], acc[r][c]);
    }
  }

  const float4 bi0 = *(const float4*)(bih + n0 + tx * 4);
  const float4 bh0 = *(const float4*)(bhh + n0 + tx * 4);
  const float4 bi1 = *(const float4*)(bih + n0 + 64 + tx * 4);
  const float4 bh1 = *(const float4*)(bhh + n0 + 64 + tx * 4);
  const float4 bb0 = make_float4(bi0.x + bh0.x, bi0.y + bh0.y, bi0.z + bh0.z, bi0.w + bh0.w);
  const float4 bb1 = make_float4(bi1.x + bh1.x, bi1.y + bh1.y, bi1.z + bh1.z, bi1.w + bh1.w);

#pragma unroll
  for (int r = 0; r < 8; r++) {
    const int m = m0 + ((r < 4) ? (ty * 4 + r) : (64 + ty * 4 + (r - 4)));
    float4* orow = (float4*)(out + (size_t)m * H_DIM + n0);
    orow[tx] = make_float4(acc[r][0] + bb0.x, acc[r][1] + bb0.y,
                           acc[r][2] + bb0.z, acc[r][3] + bb0.w);
    orow[16 + tx] = make_float4(acc[r][4] + bb1.x, acc[r][5] + bb1.y,
                                acc[r][6] + bb1.z, acc[r][7] + bb1.w);
  }
}

// ---------------- Kernel 2: recurrent scan ----------------

// 16-lane sum on the VALU pipe (DPP): quad_perm 0xB1, 0x4E, row_ror:4, :8.
__device__ __forceinline__ float row16_sum(float v) {
  int m;
  m = __builtin_amdgcn_update_dpp(0, __float_as_int(v), 0xB1, 0xF, 0xF, true);
  v += __int_as_float(m);
  m = __builtin_amdgcn_update_dpp(0, __float_as_int(v), 0x4E, 0xF, 0xF, true);
  v += __int_as_float(m);
  m = __builtin_amdgcn_update_dpp(0, __float_as_int(v), 0x124, 0xF, 0xF, true);
  v += __int_as_float(m);
  m = __builtin_amdgcn_update_dpp(0, __float_as_int(v), 0x128, 0xF, 0xF, true);
  v += __int_as_float(m);
  return v;
}

// hh accumulation: 4 rows x 8 float4 + 16-lane reduce; result valid cg<4.
__device__ __forceinline__ float hh_acc(const float* hb,
                                        const float4 (&w)[4][8], int cg) {
  float a0 = 0.f, a1 = 0.f, a2 = 0.f, a3 = 0.f;
#pragma unroll
  for (int i = 0; i < 8; i++) {
    const float4 hv = ((const float4*)hb)[i * 16 + cg];
    a0 = fmaf(w[0][i].x, hv.x, a0); a0 = fmaf(w[0][i].y, hv.y, a0);
    a0 = fmaf(w[0][i].z, hv.z, a0); a0 = fmaf(w[0][i].w, hv.w, a0);
    a1 = fmaf(w[1][i].x, hv.x, a1); a1 = fmaf(w[1][i].y, hv.y, a1);
    a1 = fmaf(w[1][i].z, hv.z, a1); a1 = fmaf(w[1][i].w, hv.w, a1);
    a2 = fmaf(w[2][i].x, hv.x, a2); a2 = fmaf(w[2][i].y, hv.y, a2);
    a2 = fmaf(w[2][i].z, hv.z, a2); a2 = fmaf(w[2][i].w, hv.w, a2);
    a3 = fmaf(w[3][i].x, hv.x, a3); a3 = fmaf(w[3][i].y, hv.y, a3);
    a3 = fmaf(w[3][i].z, hv.z, a3); a3 = fmaf(w[3][i].w, hv.w, a3);
  }
  a0 = row16_sum(a0);
  a1 = row16_sum(a1);
  a2 = row16_sum(a2);
  a3 = row16_sum(a3);
  return (cg == 0) ? a0 : (cg == 1) ? a1 : (cg == 2) ? a2 : a3;
}

__global__ __launch_bounds__(512, 2) void rnn_scan4(
    const float* __restrict__ whh, float* __restrict__ out,
    unsigned long long* __restrict__ stage) {
  __shared__ __align__(16) float hbuf[2][H_DIM];  // 4 KB h double buffer

  const int b   = blockIdx.x & 63;
  const int rb  = blockIdx.x >> 6;       // row-chunk 0..3
  const int tid = threadIdx.x;           // 0..511
  const int rg  = tid >> 4;              // 0..31
  const int cg  = tid & 15;              // 0..15
  const int j0  = rb * 128 + rg * 4;     // first of my 4 rows
  const int jj  = j0 + cg;               // publish index (cg<4 lanes)

  // spin target: one partner element each for threads 0..383 (skip own chunk)
  const int pj = (tid < rb * 128) ? tid : tid + 128;
  const bool poller = (tid < 384);

  // ---- W_hh chunk -> registers (once) ----
  float4 w[4][8];
#pragma unroll
  for (int r = 0; r < 4; r++) {
    const float4* wr = (const float4*)(whh + (size_t)(j0 + r) * H_DIM);
#pragma unroll
    for (int i = 0; i < 8; i++) w[r][i] = wr[i * 16 + cg];
  }

  float* __restrict__ outb = out + (size_t)b * H_DIM;  // t-stride = BH_DIM
  unsigned long long* __restrict__ stg0 = stage + (size_t)b * H_DIM;
  unsigned long long* __restrict__ stg1 = stage + (size_t)(64 + b) * H_DIM;

  float hlast = 0.f;

  // ---- t = 0: h_0 = relu(xw_0); publish (tag 1, parity 0) ----
  if (cg < 4) {
    const float h = fmaxf(outb[jj], 0.f);
    union { float f; unsigned int u; } cv; cv.f = h;
    __hip_atomic_store(&stg0[jj], (1ULL << 32) | (unsigned long long)cv.u,
                       __ATOMIC_RELAXED, __HIP_MEMORY_SCOPE_AGENT);
    __builtin_nontemporal_store(h, &outb[jj]);
    hbuf[0][jj] = h;
    hlast = h;
  }

  // prologue: spec poll load for t=1 (parity 0), then xw for t=1 (newer ->
  // the t=1 check's counted vmcnt does not wait for it)
  unsigned long long* slot = stg0 + pj;
  unsigned long long v = 0;
  if (poller)
    v = __hip_atomic_load(slot, __ATOMIC_RELAXED, __HIP_MEMORY_SCOPE_AGENT);
  float xwv = 0.f;
  if (cg < 4)
    xwv = __builtin_nontemporal_load(&outb[(size_t)BH_DIM + jj]);

  // ---- main scan ----
  for (int t = 1; t < T_DIM; t++) {
    const int p = (t - 1) & 1;  // parity of h_{t-1}
    const unsigned int want = (unsigned int)t;  // tag carried by h_{t-1}
    float* o_t = outb + (size_t)t * BH_DIM;

    // A. finish the poll. First check consumes the spec load issued BEFORE
    //    last iteration's stores -> counted vmcnt skips the store acks.
    if (poller) {
      while ((unsigned int)(v >> 32) != want)
        v = __hip_atomic_load(slot, __ATOMIC_RELAXED,
                              __HIP_MEMORY_SCOPE_AGENT);
      union { unsigned int u; float f; } cv; cv.u = (unsigned int)v;
      hbuf[p][pj] = cv.f;
    }

    __syncthreads();  // h_{t-1} complete in LDS

    // B. xw prefetch for t+1 (post-barrier: drains at the NEXT barrier,
    //    ~P cycles later, long retired; consumed at next publish)
    float xw_n = 0.f;
    if (cg < 4 && t + 1 < T_DIM)
      xw_n = __builtin_nontemporal_load(&outb[(size_t)(t + 1) * BH_DIM + jj]);

    // C. hh-fma + DPP reduce
    const float acc = hh_acc(hbuf[p], w, cg);

    // D. speculative poll load for t+1, issued BEFORE the publish/out
    //    stores so next iteration's check needs only vmcnt(2) (stores are
    //    newer). sched_barrier pins the order against the scheduler.
    if (poller) {
      slot = ((t & 1) ? stg1 : stg0) + pj;
      v = __hip_atomic_load(slot, __ATOMIC_RELAXED, __HIP_MEMORY_SCOPE_AGENT);
    }
    __builtin_amdgcn_sched_barrier(0);

    // E. publish h_t (tag t+1; 16 contiguous tagged words per wave)
    if (cg < 4) {
      const float h = fmaxf(acc + xwv, 0.f);
      union { float f; unsigned int u; } cv; cv.f = h;
      unsigned long long* sb = (t & 1) ? stg1 : stg0;
      __hip_atomic_store(&sb[jj],
                         ((unsigned long long)(unsigned int)(t + 1) << 32) |
                             (unsigned long long)cv.u,
                         __ATOMIC_RELAXED, __HIP_MEMORY_SCOPE_AGENT);
      __builtin_nontemporal_store(h, &o_t[jj]);  // output[t,b,j]
      hbuf[t & 1][jj] = h;    // own rows for next step
      hlast = h;
    }

    xwv = xw_n;
  }

  // h_final = h_{T-1}
  if (cg < 4) {
    __builtin_nontemporal_store(
        hlast, &out[(size_t)T_DIM * BH_DIM + (size_t)b * H_DIM + jj]);
  }
}

extern "C" void kernel_launch(void* const* d_in, const int* in_sizes, int n_in,
                              void* d_out, int out_size, void* d_ws, size_t ws_size,
                              hipStream_t stream) {
  const float* x   = (const float*)d_in[0];  // [T,B,I]
  const float* wih = (const float*)d_in[1];  // [H,I]
  const float* whh = (const float*)d_in[2];  // [H,H]
  const float* bih = (const float*)d_in[3];  // [H]
  const float* bhh = (const float*)d_in[4];  // [H]
  float* out = (float*)d_out;                // [T,B,H] output ++ [B,H] h_final
  // staging: 2 parities x 64 batches x 512 tagged 8B words = 512 KB
  unsigned long long* stage = (unsigned long long*)d_ws;

  // Pass 1: xw = x @ wih^T + bih + bhh  -> written into out[0 .. T*B*H)
  xw_gemm<<<1024, 256, 0, stream>>>(x, wih, bih, bhh, out);
  // Pass 2: scan with spec-poll-before-stores + post-barrier xw prefetch
  rnn_scan4<<<256, 512, 0, stream>>>(whh, out, stage);
}